// Round 2
// baseline (1473.198 us; speedup 1.0000x reference)
//
#include <hip/hip_runtime.h>
#include <stdint.h>

#define D_ 2048
#define H_ 16
#define HK_ 4
#define F_ 8192
#define R_ 64
#define NTOK_ 2048
#define EPS_ 1e-5f

typedef unsigned short u16;
typedef short short8 __attribute__((ext_vector_type(8)));
typedef float f32x4 __attribute__((ext_vector_type(4)));

__constant__ float NF4_TAB[16] = {
  -1.0f, -0.6961928009986877f, -0.5250730514526367f, -0.39491748809814453f,
  -0.28444138169288635f, -0.18477343022823334f, -0.09105003625154495f, 0.0f,
  0.07958029955625534f, 0.16093020141124725f, 0.24611230194568634f, 0.33791524171829224f,
  0.44070982933044434f, 0.5626170039176941f, 0.7229568362236023f, 1.0f };

static __device__ __forceinline__ float b2f(u16 u){ return __uint_as_float(((unsigned)u)<<16); }
static __device__ __forceinline__ u16 f2b(float f){
  unsigned u = __float_as_uint(f);
  return (u16)((u + 0x7fffu + ((u>>16)&1u)) >> 16);
}

// ---------------- embedding gather
__global__ void k_embed(const int* __restrict__ ids, const float* __restrict__ embed,
                        float* __restrict__ h){
  int tok = blockIdx.x;
  int id  = ids[tok];
  const float4* src = (const float4*)(embed + (size_t)id * D_);
  float4* dst = (float4*)(h + (size_t)tok * D_);
  for (int i = threadIdx.x; i < D_/4; i += 256) dst[i] = src[i];
}

// ---------------- RMSNorm
__global__ void k_rms(const float* __restrict__ h, const float* __restrict__ w,
                      u16* __restrict__ xb){
  __shared__ float red[4];
  int row = blockIdx.x, t = threadIdx.x;
  const float* hr = h + (size_t)row * D_;
  float ss = 0.f;
  for (int i = t; i < D_; i += 256){ float v = hr[i]; ss += v*v; }
  #pragma unroll
  for (int m = 32; m; m >>= 1) ss += __shfl_xor(ss, m, 64);
  if ((t & 63) == 0) red[t >> 6] = ss;
  __syncthreads();
  float sc = rsqrtf((red[0]+red[1]+red[2]+red[3]) * (1.0f/D_) + EPS_);
  for (int i = t; i < D_; i += 256) xb[(size_t)row*D_ + i] = f2b(hr[i]*sc*w[i]);
}

// ---------------- fold-dequant: W[n,k] = NF4[codes]*absmax + 2 * B@A
// MFMA version: LoRA tile computed as C'[kc][n] = sum_r At[kc][r]*B[n][r]
// via mfma_f32_16x16x32_bf16 (m=kc, n=n, k=r). Lane holds 4 consecutive kc
// per acc -> vectorized 8B dequant+store.
struct FoldSet { const int* c; const float* am; const float* A; const float* Bm; u16* W; };

static __device__ __forceinline__ void fold_tile(const int* __restrict__ codes,
    const float* __restrict__ absmax, const float* __restrict__ Amat,
    const float* __restrict__ Bmat, u16* __restrict__ W, int I, int n0, int k0){
  __shared__ u16 At[128*64];   // A^T tile (kc-major), XOR-swizzled
  __shared__ u16 Bl[128*64];   // B tile (n-major),  XOR-swizzled
  __shared__ float nf4s[16];
  int t = threadIdx.x;
  if (t < 16) nf4s[t] = NF4_TAB[t];
  // stage A^T: A is (64 x I) row-major fp32
  #pragma unroll
  for (int it = 0; it < 8; ++it){
    int fi = it*256 + t;
    int r = fi >> 5, c4 = fi & 31;
    float4 v = *(const float4*)(Amat + (size_t)r*I + k0 + c4*4);
    int kc0 = c4*4;
    At[((kc0+0)*64 + r) ^ (((kc0+0)&7)<<3)] = f2b(v.x);
    At[((kc0+1)*64 + r) ^ (((kc0+1)&7)<<3)] = f2b(v.y);
    At[((kc0+2)*64 + r) ^ (((kc0+2)&7)<<3)] = f2b(v.z);
    At[((kc0+3)*64 + r) ^ (((kc0+3)&7)<<3)] = f2b(v.w);
  }
  // stage B: (128 x 64) row-major fp32 -> bf16
  #pragma unroll
  for (int it = 0; it < 8; ++it){
    int fi = it*256 + t;
    int nl = fi >> 4, r4 = fi & 15;
    float4 v = *(const float4*)(Bmat + (size_t)(n0+nl)*R_ + r4*4);
    uint2 p; p.x = (unsigned)f2b(v.x) | ((unsigned)f2b(v.y)<<16);
    p.y = (unsigned)f2b(v.z) | ((unsigned)f2b(v.w)<<16);
    *(uint2*)&Bl[(nl*64 + r4*4) ^ ((nl&7)<<3)] = p;
  }
  __syncthreads();
  int w = t >> 6, lane = t & 63;
  int lr = lane & 15, lg = lane >> 4;
  f32x4 acc[2][8];
  #pragma unroll
  for (int mt = 0; mt < 2; ++mt)
    #pragma unroll
    for (int nt = 0; nt < 8; ++nt) acc[mt][nt] = (f32x4){0.f,0.f,0.f,0.f};
  #pragma unroll
  for (int ks = 0; ks < 64; ks += 32){
    short8 af[2], bf_[8];
    #pragma unroll
    for (int mt = 0; mt < 2; ++mt)
      af[mt] = *(const short8*)&At[((w*32 + mt*16 + lr)*64 + ks + lg*8) ^ ((lr&7)<<3)];
    #pragma unroll
    for (int nt = 0; nt < 8; ++nt)
      bf_[nt] = *(const short8*)&Bl[((nt*16 + lr)*64 + ks + lg*8) ^ ((lr&7)<<3)];
    #pragma unroll
    for (int mt = 0; mt < 2; ++mt)
      #pragma unroll
      for (int nt = 0; nt < 8; ++nt)
        acc[mt][nt] = __builtin_amdgcn_mfma_f32_16x16x32_bf16(af[mt], bf_[nt], acc[mt][nt], 0, 0, 0);
  }
  // dequant epilogue: lane owns kc = w*32+mt*16+lg*4+{0..3}, n = nt*16+lr
  int Ib = I >> 6;
  #pragma unroll
  for (int mt = 0; mt < 2; ++mt){
    int kcb = k0 + w*32 + mt*16 + lg*4;
    int kblk = kcb >> 6;
    #pragma unroll
    for (int nt = 0; nt < 8; ++nt){
      int n = n0 + nt*16 + lr;
      float am = absmax[(size_t)n*Ib + kblk];
      int4 c = *(const int4*)(codes + (size_t)n*I + kcb);
      u16 o0 = f2b(nf4s[c.x&15]*am + 2.0f*acc[mt][nt][0]);
      u16 o1 = f2b(nf4s[c.y&15]*am + 2.0f*acc[mt][nt][1]);
      u16 o2 = f2b(nf4s[c.z&15]*am + 2.0f*acc[mt][nt][2]);
      u16 o3 = f2b(nf4s[c.w&15]*am + 2.0f*acc[mt][nt][3]);
      uint2 pk; pk.x = (unsigned)o0 | ((unsigned)o1<<16);
      pk.y = (unsigned)o2 | ((unsigned)o3<<16);
      *(uint2*)(W + (size_t)n*I + kcb) = pk;
    }
  }
}

// merged fold launcher: up to 3 sets split along grid y at [y1, y2)
__global__ __launch_bounds__(256) void k_fold3(FoldSet a, FoldSet b, FoldSet c,
                                               int y1, int y2, int I){
  int y = blockIdx.y;
  FoldSet s = (y < y1) ? a : (y < y2) ? b : c;
  int n0 = (y < y1) ? y*128 : (y < y2) ? (y-y1)*128 : (y-y2)*128;
  fold_tile(s.c, s.am, s.A, s.Bm, s.W, I, n0, blockIdx.x*128);
}

// ---------------- main GEMM: VGPR-staged double-buffer, depth-2 prefetch,
// one raw s_barrier per iter with lgkmcnt-only wait (no vmcnt drain).
// C[m,n] = sum_k A[m,k]*B[n,k], both bf16 row-major ld=K.
// EPI 0: C0=bf16  EPI 1: Cf+=acc  EPI 2: split-N qkv  EPI 3: split-N kv-only
// EPI 4: C0 = silu(C1)*acc (bf16)
template<int EPI>
__global__ __launch_bounds__(256,3) void k_gemm(const u16* __restrict__ A,
      const u16* __restrict__ B, float* __restrict__ Cf, u16* __restrict__ C0,
      u16* __restrict__ C1, u16* __restrict__ C2, int M, int N, int K){
  __shared__ u16 SA[2][128*32];
  __shared__ u16 SB[2][128*32];
  int t = threadIdx.x;
  int n0 = blockIdx.x*128, m0 = blockIdx.y*128;
  int w = t >> 6, lane = t & 63;
  int mw = (w >> 1)*64, nw = (w & 1)*64;
  int lr = lane & 15, lg = lane >> 4;
  f32x4 acc[4][4];
  #pragma unroll
  for (int mt = 0; mt < 4; ++mt)
    #pragma unroll
    for (int nt = 0; nt < 4; ++nt) acc[mt][nt] = (f32x4){0.f,0.f,0.f,0.f};
  const u16* Ag = A + (size_t)(m0 + (t>>2))*K + (t&3)*8;
  const u16* Bg = B + (size_t)(n0 + (t>>2))*K + (t&3)*8;
  int t8 = t*8;
  int niter = K >> 5;   // always even (>=64)

  uint4 ra0, ra1, rb0, rb1;
  uint4 sa0, sa1, sb0, sb1;
  auto gload = [&](int it, uint4& a0, uint4& a1, uint4& b0, uint4& b1){
    int kb = it*32;
    a0 = *(const uint4*)(Ag + kb);
    a1 = *(const uint4*)(Ag + (size_t)64*K + kb);
    b0 = *(const uint4*)(Bg + kb);
    b1 = *(const uint4*)(Bg + (size_t)64*K + kb);
  };
  gload(0, ra0, ra1, rb0, rb1);
  gload(1, sa0, sa1, sb0, sb1);

  auto step = [&](int buf, uint4& a0, uint4& a1, uint4& b0, uint4& b1, int pf){
    *(uint4*)&SA[buf][t8]        = a0;
    *(uint4*)&SA[buf][2048 + t8] = a1;
    *(uint4*)&SB[buf][t8]        = b0;
    *(uint4*)&SB[buf][2048 + t8] = b1;
    __builtin_amdgcn_s_waitcnt(0xC07F);   // lgkmcnt(0) only
    __builtin_amdgcn_s_barrier();
    gload(pf, a0, a1, b0, b1);
    short8 af[4], bf_[4];
    #pragma unroll
    for (int mt = 0; mt < 4; ++mt) af[mt]  = *(const short8*)&SA[buf][(mw + mt*16 + lr)*32 + lg*8];
    #pragma unroll
    for (int nt = 0; nt < 4; ++nt) bf_[nt] = *(const short8*)&SB[buf][(nw + nt*16 + lr)*32 + lg*8];
    #pragma unroll
    for (int mt = 0; mt < 4; ++mt)
      #pragma unroll
      for (int nt = 0; nt < 4; ++nt)
        acc[mt][nt] = __builtin_amdgcn_mfma_f32_16x16x32_bf16(af[mt], bf_[nt], acc[mt][nt], 0, 0, 0);
  };

  for (int k = 0; k < niter; k += 2){
    step(0, ra0, ra1, rb0, rb1, (k+2 < niter) ? k+2 : k);
    step(1, sa0, sa1, sb0, sb1, (k+3 < niter) ? k+3 : k+1);
  }

  // epilogue
  u16* cb_ = C0; int ldc = N; int coff = n0;
  if (EPI == 2){
    if (n0 < 2048)      { cb_ = C0; ldc = 2048; coff = n0; }
    else if (n0 < 2560) { cb_ = C1; ldc = 512;  coff = n0 - 2048; }
    else                { cb_ = C2; ldc = 512;  coff = n0 - 2560; }
  }
  if (EPI == 3){
    if (n0 < 512)       { cb_ = C1; ldc = 512;  coff = n0; }
    else                { cb_ = C2; ldc = 512;  coff = n0 - 512; }
  }
  #pragma unroll
  for (int mt = 0; mt < 4; ++mt)
    #pragma unroll
    for (int nt = 0; nt < 4; ++nt){
      int cl = nw + nt*16 + lr;
      #pragma unroll
      for (int rg = 0; rg < 4; ++rg){
        int row = m0 + mw + mt*16 + lg*4 + rg;
        float v = acc[mt][nt][rg];
        if (EPI == 1){
          Cf[(size_t)row*N + n0 + cl] += v;
        } else if (EPI == 4){
          size_t idx = (size_t)row*ldc + coff + cl;
          float g = b2f(C1[idx]);
          cb_[idx] = f2b((g/(1.0f+__expf(-g)))*v);
        } else {
          cb_[(size_t)row*ldc + coff + cl] = f2b(v);
        }
      }
    }
}

// ---------------- skinny GEMM for M=16 (one 16x16 MFMA frag per wave)
// C = A(16 x K) @ B(N x K)^T.  OUT=0: bf16 store. OUT=1: f32 atomicAdd into Hf
// at gathered rows. OUT=3: Cb = silu(Cb)*acc. GA=1: gather A rows via rows[].
template<int OUT, int GA, int KC>
__global__ __launch_bounds__(256) void k_skinny(const u16* __restrict__ A,
      const u16* __restrict__ B, float* __restrict__ Hf, u16* __restrict__ Cb,
      const int* __restrict__ rows, int N, int K){
  int w = threadIdx.x >> 6, lane = threadIdx.x & 63;
  int lr = lane & 15, lg = lane >> 4;
  int n0 = blockIdx.x*64 + w*16;
  int kbase = blockIdx.y * KC;
  int ar = GA ? rows[lr] : lr;
  f32x4 ac0 = (f32x4){0.f,0.f,0.f,0.f};
  f32x4 ac1 = (f32x4){0.f,0.f,0.f,0.f};
  const u16* Ap = A + (size_t)ar*K + kbase + lg*8;
  const u16* Bp = B + (size_t)(n0 + lr)*K + kbase + lg*8;
  #pragma unroll 8
  for (int k = 0; k < KC; k += 64){
    ac0 = __builtin_amdgcn_mfma_f32_16x16x32_bf16(*(const short8*)(Ap + k),
            *(const short8*)(Bp + k), ac0, 0, 0, 0);
    ac1 = __builtin_amdgcn_mfma_f32_16x16x32_bf16(*(const short8*)(Ap + k + 32),
            *(const short8*)(Bp + k + 32), ac1, 0, 0, 0);
  }
  f32x4 acc = ac0 + ac1;
  #pragma unroll
  for (int rg = 0; rg < 4; ++rg){
    int m = lg*4 + rg;
    if (OUT == 0){
      Cb[(size_t)m*N + n0 + lr] = f2b(acc[rg]);
    } else if (OUT == 1){
      atomicAdd(&Hf[(size_t)rows[m]*D_ + n0 + lr], acc[rg]);
    } else {
      size_t idx = (size_t)m*N + n0 + lr;
      float g = b2f(Cb[idx]);
      Cb[idx] = f2b((g/(1.0f+__expf(-g)))*acc[rg]);
    }
  }
}

// ---------------- last-token row indices
__global__ void k_rows(const int* __restrict__ mask, int* __restrict__ rows){
  int b = threadIdx.x;
  if (b < 16){
    int c = 0;
    for (int i = 0; i < 128; ++i) c += (mask[b*128+i] > 0);
    rows[b] = b*128 + c - 1;
  }
}

// ---------------- RMSNorm on 16 gathered rows -> compact
__global__ void k_rms16(const float* __restrict__ h, const float* __restrict__ w,
                        const int* __restrict__ rows, u16* __restrict__ xq){
  __shared__ float red[4];
  int m = blockIdx.x, t = threadIdx.x;
  const float* hr = h + (size_t)rows[m] * D_;
  float ss = 0.f;
  for (int i = t; i < D_; i += 256){ float v = hr[i]; ss += v*v; }
  #pragma unroll
  for (int mm = 32; mm; mm >>= 1) ss += __shfl_xor(ss, mm, 64);
  if ((t & 63) == 0) red[t >> 6] = ss;
  __syncthreads();
  float sc = rsqrtf((red[0]+red[1]+red[2]+red[3]) * (1.0f/D_) + EPS_);
  for (int i = t; i < D_; i += 256) xq[(size_t)m*D_ + i] = f2b(hr[i]*sc*w[i]);
}

// ---------------- RoPE in-place on bf16 [tok][nh*128]
__global__ void k_rope(u16* __restrict__ x, int nh){
  int i = blockIdx.x*256 + threadIdx.x;
  int d = i & 63; int rem = i >> 6; int hh = rem % nh; int tok = rem / nh;
  int s = tok & 127;
  size_t base = (size_t)tok*nh*128 + hh*128 + d;
  float x1 = b2f(x[base]), x2 = b2f(x[base+64]);
  float inv = exp2f(-(float)d * 0.20762050581352868f);
  float ang = (float)s * inv;
  float sn = sinf(ang), cs = cosf(ang);
  x[base]      = f2b(x1*cs - x2*sn);
  x[base+64]   = f2b(x2*cs + x1*sn);
}

// ---------------- RoPE on compact q (16 rows x 16 heads x 128)
__global__ void k_rope16(u16* __restrict__ x, const int* __restrict__ rows){
  int i = blockIdx.x*256 + threadIdx.x;      // 16384 total
  int d = i & 63; int hh = (i >> 6) & 15; int m = i >> 10;
  int s = rows[m] & 127;
  size_t base = (size_t)m*2048 + hh*128 + d;
  float x1 = b2f(x[base]), x2 = b2f(x[base+64]);
  float inv = exp2f(-(float)d * 0.20762050581352868f);
  float ang = (float)s * inv;
  float sn = sinf(ang), cs = cosf(ang);
  x[base]      = f2b(x1*cs - x2*sn);
  x[base+64]   = f2b(x2*cs + x1*sn);
}

// ---------------- attention: one block per (b, head); S=128, HD=128 (full M)
__global__ __launch_bounds__(256) void k_attn(const u16* __restrict__ q,
      const u16* __restrict__ kk, const u16* __restrict__ vv,
      const int* __restrict__ mask, u16* __restrict__ ctx){
  __shared__ u16 QP[128*128];
  __shared__ u16 KV[128*128];
  int b = blockIdx.y, h = blockIdx.x;
  int t = threadIdx.x, w = t >> 6, lane = t & 63;
  int lr = lane & 15, lg = lane >> 4;
  #pragma unroll
  for (int it = 0; it < 8; ++it){
    int fi = it*256 + t; int s = fi >> 4, c8 = fi & 15;
    *(uint4*)&QP[s*128 + c8*8] = *(const uint4*)(q  + (size_t)(b*128+s)*2048 + h*128 + c8*8);
    *(uint4*)&KV[s*128 + c8*8] = *(const uint4*)(kk + (size_t)(b*128+s)*512 + (h>>2)*128 + c8*8);
  }
  __syncthreads();
  f32x4 sac[2][8];
  #pragma unroll
  for (int mt = 0; mt < 2; ++mt)
    #pragma unroll
    for (int nt = 0; nt < 8; ++nt) sac[mt][nt] = (f32x4){0.f,0.f,0.f,0.f};
  for (int ks = 0; ks < 128; ks += 32){
    short8 a[2], bb[8];
    #pragma unroll
    for (int mt = 0; mt < 2; ++mt) a[mt] = *(const short8*)&QP[(w*32 + mt*16 + lr)*128 + ks + lg*8];
    #pragma unroll
    for (int nt = 0; nt < 8; ++nt) bb[nt] = *(const short8*)&KV[(nt*16 + lr)*128 + ks + lg*8];
    #pragma unroll
    for (int mt = 0; mt < 2; ++mt)
      #pragma unroll
      for (int nt = 0; nt < 8; ++nt)
        sac[mt][nt] = __builtin_amdgcn_mfma_f32_16x16x32_bf16(a[mt], bb[nt], sac[mt][nt], 0, 0, 0);
  }
  const float NEG = -1e9f, scl = 0.08838834764831845f;
  float mbias[8];
  #pragma unroll
  for (int nt = 0; nt < 8; ++nt) mbias[nt] = (mask[b*128 + nt*16 + lr] > 0) ? 0.f : NEG;
  #pragma unroll
  for (int mt = 0; mt < 2; ++mt)
    #pragma unroll
    for (int rg = 0; rg < 4; ++rg){
      int row = w*32 + mt*16 + lg*4 + rg;
      float vvv[8]; float mx = -3e38f;
      #pragma unroll
      for (int nt = 0; nt < 8; ++nt){
        int col = nt*16 + lr;
        float s_ = sac[mt][nt][rg]*scl + ((col <= row) ? mbias[nt] : NEG);
        vvv[nt] = s_; mx = fmaxf(mx, s_);
      }
      #pragma unroll
      for (int m_ = 1; m_ < 16; m_ <<= 1) mx = fmaxf(mx, __shfl_xor(mx, m_, 64));
      float sum = 0.f;
      #pragma unroll
      for (int nt = 0; nt < 8; ++nt){ vvv[nt] = __expf(vvv[nt]-mx); sum += vvv[nt]; }
      #pragma unroll
      for (int m_ = 1; m_ < 16; m_ <<= 1) sum += __shfl_xor(sum, m_, 64);
      float inv = 1.0f/sum;
      #pragma unroll
      for (int nt = 0; nt < 8; ++nt) QP[row*128 + nt*16 + lr] = f2b(vvv[nt]*inv);
    }
  __syncthreads();
  #pragma unroll
  for (int it = 0; it < 8; ++it){
    int fi = it*256 + t; int s = fi >> 4, c8 = fi & 15;
    u16 tmp[8];
    *(uint4*)tmp = *(const uint4*)(vv + (size_t)(b*128+s)*512 + (h>>2)*128 + c8*8);
    #pragma unroll
    for (int j = 0; j < 8; ++j) KV[(c8*8+j)*128 + s] = tmp[j];
  }
  __syncthreads();
  f32x4 oac[2][8];
  #pragma unroll
  for (int mt = 0; mt < 2; ++mt)
    #pragma unroll
    for (int nt = 0; nt < 8; ++nt) oac[mt][nt] = (f32x4){0.f,0.f,0.f,0.f};
  for (int ks = 0; ks < 128; ks += 32){
    short8 a[2], bb[8];
    #pragma unroll
    for (int mt = 0; mt < 2; ++mt) a[mt] = *(const short8*)&QP[(w*32 + mt*16 + lr)*128 + ks + lg*8];
    #pragma unroll
    for (int nt = 0; nt < 8; ++nt) bb[nt] = *(const short8*)&KV[(nt*16 + lr)*128 + ks + lg*8];
    #pragma unroll
    for (int mt = 0; mt < 2; ++mt)
      #pragma unroll
      for (int nt = 0; nt < 8; ++nt)
        oac[mt][nt] = __builtin_amdgcn_mfma_f32_16x16x32_bf16(a[mt], bb[nt], oac[mt][nt], 0, 0, 0);
  }
  #pragma unroll
  for (int mt = 0; mt < 2; ++mt)
    #pragma unroll
    for (int nt = 0; nt < 8; ++nt)
      #pragma unroll
      for (int rg = 0; rg < 4; ++rg){
        int row = w*32 + mt*16 + lg*4 + rg;
        int col = nt*16 + lr;
        ctx[(size_t)(b*128+row)*2048 + h*128 + col] = f2b(oac[mt][nt][rg]);
      }
}

// ---------------- single-query attention for the 16 gathered rows
__global__ void k_attn1(const u16* __restrict__ qc, const u16* __restrict__ kk,
      const u16* __restrict__ vv, const int* __restrict__ mask,
      const int* __restrict__ rows, u16* __restrict__ out){
  __shared__ float ps[128];
  __shared__ float red2[2];
  int h = blockIdx.x, b = blockIdx.y, t = threadIdx.x;
  int pos = rows[b] & 127;
  const u16* qrow = qc + (size_t)b*2048 + h*128;
  const u16* krow = kk + (size_t)(b*128 + t)*512 + (h>>2)*128;
  float acc = 0.f;
  #pragma unroll
  for (int d0 = 0; d0 < 128; d0 += 8){
    short8 qa = *(const short8*)(qrow + d0);
    short8 ka = *(const short8*)(krow + d0);
    #pragma unroll
    for (int j = 0; j < 8; ++j) acc += b2f((u16)qa[j]) * b2f((u16)ka[j]);
  }
  bool keep = (t <= pos) && (mask[b*128 + t] > 0);
  float s_ = keep ? acc * 0.08838834764831845f : -1e9f;
  float mx = s_;
  #pragma unroll
  for (int m_ = 1; m_ < 64; m_ <<= 1) mx = fmaxf(mx, __shfl_xor(mx, m_, 64));
  if ((t & 63) == 0) red2[t >> 6] = mx;
  __syncthreads();
  mx = fmaxf(red2[0], red2[1]);
  float p = __expf(s_ - mx);
  float sum = p;
  #pragma unroll
  for (int m_ = 1; m_ < 64; m_ <<= 1) sum += __shfl_xor(sum, m_, 64);
  __syncthreads();
  if ((t & 63) == 0) red2[t >> 6] = sum;
  __syncthreads();
  float inv = 1.f / (red2[0] + red2[1]);
  ps[t] = p * inv;
  __syncthreads();
  float o = 0.f;
  const u16* vbase = vv + (size_t)b*128*512 + (h>>2)*128 + t;
  for (int s = 0; s < 128; s += 4){
    o += ps[s]   * b2f(vbase[(size_t)(s  )*512]);
    o += ps[s+1] * b2f(vbase[(size_t)(s+1)*512]);
    o += ps[s+2] * b2f(vbase[(size_t)(s+2)*512]);
    o += ps[s+3] * b2f(vbase[(size_t)(s+3)*512]);
  }
  out[(size_t)b*2048 + h*128 + t] = f2b(o);
}

// ---------------- final norm + last-token gather
__global__ void k_final(const float* __restrict__ h, const int* __restrict__ mask,
                        const float* __restrict__ w, float* __restrict__ out){
  __shared__ float red[4]; __shared__ int rowsh;
  int b = blockIdx.x, t = threadIdx.x;
  if (t == 0){
    int c = 0;
    for (int i = 0; i < 128; ++i) c += (mask[b*128+i] > 0);
    rowsh = b*128 + c - 1;
  }
  __syncthreads();
  const float* hr = h + (size_t)rowsh*D_;
  float ss = 0.f;
  for (int i = t; i < D_; i += 256){ float x = hr[i]; ss += x*x; }
  #pragma unroll
  for (int m = 32; m; m >>= 1) ss += __shfl_xor(ss, m, 64);
  if ((t & 63) == 0) red[t >> 6] = ss;
  __syncthreads();
  float sc = rsqrtf((red[0]+red[1]+red[2]+red[3]) * (1.0f/D_) + EPS_);
  for (int i = t; i < D_; i += 256) out[(size_t)b*D_ + i] = hr[i]*sc*w[i];
}

extern "C" void kernel_launch(void* const* d_in, const int* in_sizes, int n_in,
                              void* d_out, int out_size, void* d_ws, size_t ws_size,
                              hipStream_t stream) {
  const int*   ids       = (const int*)  d_in[0];
  const int*   mask      = (const int*)  d_in[1];
  const float* embed     = (const float*)d_in[2];
  const float* attn_norm = (const float*)d_in[3];
  const float* mlp_norm  = (const float*)d_in[4];
  const float* fin_norm  = (const float*)d_in[5];
  struct QW { const int* c; const float* am; const float* A; const float* B; };
  auto qw = [&](int i){ return QW{(const int*)d_in[i], (const float*)d_in[i+1],
                                  (const float*)d_in[i+2], (const float*)d_in[i+3]}; };
  QW Wq = qw(6), Wk = qw(10), Wv = qw(14), Wo = qw(18), Wg = qw(22), Wu = qw(26), Wd = qw(30);

  // workspace layout
  char* ws = (char*)d_ws;
  float* h  = (float*)(ws);                       // 16 MB
  u16* xb   = (u16*)(ws + 16777216);              // 8 MB (x / ctx)
  u16* qb   = (u16*)(ws + 25165824);              // 8 MB
  u16* kb_  = (u16*)(ws + 33554432);              // 2 MB
  u16* vb   = (u16*)(ws + 35651584);              // 2 MB
  u16* gb   = (u16*)(ws + 37748736);              // 32 MB
  u16* Wb   = (u16*)(ws + 104857600);             // 32 MB (folded weights)
  // compact (layer-1) buffers
  int* rowsi = (int*)(ws + 138412032);            // 64 B
  u16* xq    = (u16*)(ws + 138413056);            // 64 KB
  u16* qc    = (u16*)(ws + 138478592);            // 64 KB
  u16* cc    = (u16*)(ws + 138544128);            // 64 KB
  u16* g16   = (u16*)(ws + 138609664);            // 256 KB
  u16* Wb2   = (u16*)(ws + 167772160);            // 32 MB (second folded buffer)

  auto fs = [&](QW W_, int l, int O, int I, u16* dst){
    return FoldSet{ W_.c + (size_t)l*O*I, W_.am + (size_t)l*O*(I>>6),
                    W_.A + (size_t)l*R_*I, W_.B + (size_t)l*O*R_, dst };
  };

  k_embed<<<NTOK_, 256, 0, stream>>>(ids, embed, h);

  for (int l = 0; l < 2; ++l){
    // ---- attention block: fold q,k,v stacked into Wb (3072 x 2048), one launch
    k_rms<<<NTOK_, 256, 0, stream>>>(h, attn_norm + l*D_, xb);
    {
      FoldSet fq = fs(Wq, l, D_, D_, Wb);
      FoldSet fk = fs(Wk, l, 512, D_, Wb + (size_t)2048*D_);
      FoldSet fv = fs(Wv, l, 512, D_, Wb + (size_t)2560*D_);
      k_fold3<<<dim3(16,24), 256, 0, stream>>>(fq, fk, fv, 16, 20, D_);
    }

    if (l == 0){
      k_gemm<2><<<dim3(24,16), 256, 0, stream>>>(xb, Wb, nullptr, qb, kb_, vb, NTOK_, 3072, D_);
      k_rope<<<8192, 256, 0, stream>>>(qb, H_);
      k_rope<<<2048, 256, 0, stream>>>(kb_, HK_);
      k_attn<<<dim3(16,16), 256, 0, stream>>>(qb, kb_, vb, mask, xb);  // ctx -> xb
      {
        FoldSet fo = fs(Wo, l, D_, D_, Wb);
        k_fold3<<<dim3(16,16), 256, 0, stream>>>(fo, fo, fo, 9999, 9999, D_);
      }
      k_gemm<1><<<dim3(16,16), 256, 0, stream>>>(xb, Wb, h, nullptr, nullptr, nullptr, NTOK_, D_, D_);
      // ---- MLP block: gate->Wb, up->Wb2, one fold launch
      k_rms<<<NTOK_, 256, 0, stream>>>(h, mlp_norm + l*D_, xb);
      {
        FoldSet fg = fs(Wg, l, F_, D_, Wb);
        FoldSet fu = fs(Wu, l, F_, D_, Wb2);
        k_fold3<<<dim3(16,128), 256, 0, stream>>>(fg, fu, fu, 64, 64, D_);
      }
      k_gemm<0><<<dim3(64,16), 256, 0, stream>>>(xb, Wb,  nullptr, gb, nullptr, nullptr, NTOK_, F_, D_);
      k_gemm<4><<<dim3(64,16), 256, 0, stream>>>(xb, Wb2, nullptr, gb, gb, nullptr, NTOK_, F_, D_);
      {
        FoldSet fd = fs(Wd, l, D_, F_, Wb);
        k_fold3<<<dim3(64,16), 256, 0, stream>>>(fd, fd, fd, 9999, 9999, F_);
      }
      k_gemm<1><<<dim3(16,16), 256, 0, stream>>>(gb, Wb, h, nullptr, nullptr, nullptr, NTOK_, D_, F_);
    } else {
      // last layer: only the 16 last-token rows feed the output.
      k_gemm<3><<<dim3(8,16), 256, 0, stream>>>(xb, Wb + (size_t)2048*D_, nullptr, nullptr,
          kb_, vb, NTOK_, 1024, D_);
      k_rows<<<1, 64, 0, stream>>>(mask, rowsi);
      k_skinny<0,1,2048><<<dim3(32,1), 256, 0, stream>>>(xb, Wb, nullptr, qc, rowsi, D_, D_);
      k_rope16<<<64, 256, 0, stream>>>(qc, rowsi);
      k_rope<<<2048, 256, 0, stream>>>(kb_, HK_);
      k_attn1<<<dim3(16,16), 128, 0, stream>>>(qc, kb_, vb, mask, rowsi, cc);
      {
        FoldSet fo = fs(Wo, l, D_, D_, Wb);
        k_fold3<<<dim3(16,16), 256, 0, stream>>>(fo, fo, fo, 9999, 9999, D_);
      }
      k_skinny<1,0,2048><<<dim3(32,1), 256, 0, stream>>>(cc, Wb, h, nullptr, rowsi, D_, D_);
      // ---- MLP on 16 rows
      k_rms16<<<16, 256, 0, stream>>>(h, mlp_norm + l*D_, rowsi, xq);
      {
        FoldSet fg = fs(Wg, l, F_, D_, Wb);
        FoldSet fu = fs(Wu, l, F_, D_, Wb2);
        k_fold3<<<dim3(16,128), 256, 0, stream>>>(fg, fu, fu, 64, 64, D_);
      }
      k_skinny<0,0,2048><<<dim3(128,1), 256, 0, stream>>>(xq, Wb,  nullptr, g16, rowsi, F_, D_);
      k_skinny<3,0,2048><<<dim3(128,1), 256, 0, stream>>>(xq, Wb2, nullptr, g16, rowsi, F_, D_);
      {
        FoldSet fd = fs(Wd, l, D_, F_, Wb);
        k_fold3<<<dim3(64,16), 256, 0, stream>>>(fd, fd, fd, 9999, 9999, F_);
      }
      k_skinny<1,0,2048><<<dim3(32,4), 256, 0, stream>>>(g16, Wb, h, nullptr, rowsi, D_, F_);
    }
  }
  k_final<<<16, 256, 0, stream>>>(h, mask, fin_norm, (float*)d_out);
}

// Round 3
// 1298.249 us; speedup vs baseline: 1.1348x; 1.1348x over previous
//
#include <hip/hip_runtime.h>
#include <stdint.h>

#define D_ 2048
#define H_ 16
#define HK_ 4
#define F_ 8192
#define R_ 64
#define NTOK_ 2048
#define EPS_ 1e-5f

typedef unsigned short u16;
typedef short short8 __attribute__((ext_vector_type(8)));
typedef float f32x4 __attribute__((ext_vector_type(4)));

__constant__ float NF4_TAB[16] = {
  -1.0f, -0.6961928009986877f, -0.5250730514526367f, -0.39491748809814453f,
  -0.28444138169288635f, -0.18477343022823334f, -0.09105003625154495f, 0.0f,
  0.07958029955625534f, 0.16093020141124725f, 0.24611230194568634f, 0.33791524171829224f,
  0.44070982933044434f, 0.5626170039176941f, 0.7229568362236023f, 1.0f };

static __device__ __forceinline__ float b2f(u16 u){ return __uint_as_float(((unsigned)u)<<16); }
static __device__ __forceinline__ u16 f2b(float f){
  unsigned u = __float_as_uint(f);
  return (u16)((u + 0x7fffu + ((u>>16)&1u)) >> 16);
}

// ---------------- embedding gather
__global__ void k_embed(const int* __restrict__ ids, const float* __restrict__ embed,
                        float* __restrict__ h){
  int tok = blockIdx.x;
  int id  = ids[tok];
  const float4* src = (const float4*)(embed + (size_t)id * D_);
  float4* dst = (float4*)(h + (size_t)tok * D_);
  for (int i = threadIdx.x; i < D_/4; i += 256) dst[i] = src[i];
}

// ---------------- RMSNorm
__global__ void k_rms(const float* __restrict__ h, const float* __restrict__ w,
                      u16* __restrict__ xb){
  __shared__ float red[4];
  int row = blockIdx.x, t = threadIdx.x;
  const float* hr = h + (size_t)row * D_;
  float ss = 0.f;
  for (int i = t; i < D_; i += 256){ float v = hr[i]; ss += v*v; }
  #pragma unroll
  for (int m = 32; m; m >>= 1) ss += __shfl_xor(ss, m, 64);
  if ((t & 63) == 0) red[t >> 6] = ss;
  __syncthreads();
  float sc = rsqrtf((red[0]+red[1]+red[2]+red[3]) * (1.0f/D_) + EPS_);
  for (int i = t; i < D_; i += 256) xb[(size_t)row*D_ + i] = f2b(hr[i]*sc*w[i]);
}

// ---------------- fold-dequant: W[n,k] = NF4[codes]*absmax + 2 * B@A
// LoRA tile via MFMA (C'[kc][n] = sum_r At[kc][r]*B[n][r]), then f32 LDS
// round-trip (2 halves) so the dequant epilogue keeps R1's coalesced
// per-row access for codes/W (codes = dominant HBM stream).
struct FoldSet { const int* c; const float* am; const float* A; const float* Bm; u16* W; };

static __device__ __forceinline__ void fold_tile(const int* __restrict__ codes,
    const float* __restrict__ absmax, const float* __restrict__ Amat,
    const float* __restrict__ Bmat, u16* __restrict__ W, int I, int n0, int k0){
  __shared__ float Cl[64*132];          // 33792 B; aliased for staging
  __shared__ float nf4s[16];
  u16* At = (u16*)Cl;                   // 128*64 u16 = 16 KB
  u16* Bl = (u16*)Cl + 128*64;          // 128*64 u16 = 16 KB
  int t = threadIdx.x;
  if (t < 16) nf4s[t] = NF4_TAB[t];
  // stage A^T: A is (64 x I) row-major fp32, XOR-swizzled rows of 64 bf16
  #pragma unroll
  for (int it = 0; it < 8; ++it){
    int fi = it*256 + t;
    int r = fi >> 5, c4 = fi & 31;
    float4 v = *(const float4*)(Amat + (size_t)r*I + k0 + c4*4);
    int kc0 = c4*4;
    At[((kc0+0)*64 + r) ^ (((kc0+0)&7)<<3)] = f2b(v.x);
    At[((kc0+1)*64 + r) ^ (((kc0+1)&7)<<3)] = f2b(v.y);
    At[((kc0+2)*64 + r) ^ (((kc0+2)&7)<<3)] = f2b(v.z);
    At[((kc0+3)*64 + r) ^ (((kc0+3)&7)<<3)] = f2b(v.w);
  }
  // stage B: (128 x 64) row-major fp32 -> bf16, XOR-swizzled
  #pragma unroll
  for (int it = 0; it < 8; ++it){
    int fi = it*256 + t;
    int nl = fi >> 4, r4 = fi & 15;
    float4 v = *(const float4*)(Bmat + (size_t)(n0+nl)*R_ + r4*4);
    uint2 p; p.x = (unsigned)f2b(v.x) | ((unsigned)f2b(v.y)<<16);
    p.y = (unsigned)f2b(v.z) | ((unsigned)f2b(v.w)<<16);
    *(uint2*)&Bl[(nl*64 + r4*4) ^ ((nl&7)<<3)] = p;
  }
  __syncthreads();
  int w = t >> 6, lane = t & 63;
  int lr = lane & 15, lg = lane >> 4;
  f32x4 acc[2][8];
  #pragma unroll
  for (int mt = 0; mt < 2; ++mt)
    #pragma unroll
    for (int nt = 0; nt < 8; ++nt) acc[mt][nt] = (f32x4){0.f,0.f,0.f,0.f};
  #pragma unroll
  for (int ks = 0; ks < 64; ks += 32){
    short8 af[2], bf_[8];
    #pragma unroll
    for (int mt = 0; mt < 2; ++mt)
      af[mt] = *(const short8*)&At[((w*32 + mt*16 + lr)*64 + ks + lg*8) ^ ((lr&7)<<3)];
    #pragma unroll
    for (int nt = 0; nt < 8; ++nt)
      bf_[nt] = *(const short8*)&Bl[((nt*16 + lr)*64 + ks + lg*8) ^ ((lr&7)<<3)];
    #pragma unroll
    for (int mt = 0; mt < 2; ++mt)
      #pragma unroll
      for (int nt = 0; nt < 8; ++nt)
        acc[mt][nt] = __builtin_amdgcn_mfma_f32_16x16x32_bf16(af[mt], bf_[nt], acc[mt][nt], 0, 0, 0);
  }
  // two n-halves: dump acc -> Cl[nl][kc], then coalesced dequant epilogue
  int tk = t & 15, tn2 = t >> 4;
  int Ib = I >> 6;
  int kcb = k0 + tk*8;
  int kblk = kcb >> 6;
  #pragma unroll
  for (int half = 0; half < 2; ++half){
    __syncthreads();   // waves done reading At/Bl (h0) / prev-half Cl (h1)
    #pragma unroll
    for (int mt = 0; mt < 2; ++mt)
      #pragma unroll
      for (int nt2 = 0; nt2 < 4; ++nt2)
        *(f32x4*)&Cl[(nt2*16 + lr)*132 + w*32 + mt*16 + lg*4] = acc[mt][half*4 + nt2];
    __syncthreads();
    #pragma unroll
    for (int j = 0; j < 4; ++j){
      int nl = tn2*4 + j;
      int n = n0 + half*64 + nl;
      float am = absmax[(size_t)n*Ib + kblk];
      int4 c0 = *(const int4*)(codes + (size_t)n*I + kcb);
      int4 c1 = *(const int4*)(codes + (size_t)n*I + kcb + 4);
      const float* L = &Cl[nl*132 + tk*8];
      u16 o[8];
      o[0]=f2b(nf4s[c0.x&15]*am + 2.0f*L[0]);
      o[1]=f2b(nf4s[c0.y&15]*am + 2.0f*L[1]);
      o[2]=f2b(nf4s[c0.z&15]*am + 2.0f*L[2]);
      o[3]=f2b(nf4s[c0.w&15]*am + 2.0f*L[3]);
      o[4]=f2b(nf4s[c1.x&15]*am + 2.0f*L[4]);
      o[5]=f2b(nf4s[c1.y&15]*am + 2.0f*L[5]);
      o[6]=f2b(nf4s[c1.z&15]*am + 2.0f*L[6]);
      o[7]=f2b(nf4s[c1.w&15]*am + 2.0f*L[7]);
      uint4 pk;
      pk.x=(unsigned)o[0]|((unsigned)o[1]<<16); pk.y=(unsigned)o[2]|((unsigned)o[3]<<16);
      pk.z=(unsigned)o[4]|((unsigned)o[5]<<16); pk.w=(unsigned)o[6]|((unsigned)o[7]<<16);
      *(uint4*)(W + (size_t)n*I + kcb) = pk;
    }
  }
}

// merged fold launcher: up to 3 sets split along grid y at [y1, y2)
__global__ __launch_bounds__(256) void k_fold3(FoldSet a, FoldSet b, FoldSet c,
                                               int y1, int y2, int I){
  int y = blockIdx.y;
  FoldSet s = (y < y1) ? a : (y < y2) ? b : c;
  int n0 = (y < y1) ? y*128 : (y < y2) ? (y-y1)*128 : (y-y2)*128;
  fold_tile(s.c, s.am, s.A, s.Bm, s.W, I, n0, blockIdx.x*128);
}

// ---------------- main GEMM: VGPR-staged double-buffer, depth-2 prefetch,
// one raw s_barrier per iter with lgkmcnt-only wait (no vmcnt drain).
// C[m,n] = sum_k A[m,k]*B[n,k], both bf16 row-major ld=K.
// EPI 0: C0=bf16  EPI 1: Cf+=acc  EPI 2: split-N qkv  EPI 3: split-N kv-only
// EPI 4: C0 = silu(C1)*acc (bf16)
template<int EPI>
__global__ __launch_bounds__(256,3) void k_gemm(const u16* __restrict__ A,
      const u16* __restrict__ B, float* __restrict__ Cf, u16* __restrict__ C0,
      u16* __restrict__ C1, u16* __restrict__ C2, int M, int N, int K){
  __shared__ u16 SA[2][128*32];
  __shared__ u16 SB[2][128*32];
  int t = threadIdx.x;
  int n0 = blockIdx.x*128, m0 = blockIdx.y*128;
  int w = t >> 6, lane = t & 63;
  int mw = (w >> 1)*64, nw = (w & 1)*64;
  int lr = lane & 15, lg = lane >> 4;
  f32x4 acc[4][4];
  #pragma unroll
  for (int mt = 0; mt < 4; ++mt)
    #pragma unroll
    for (int nt = 0; nt < 4; ++nt) acc[mt][nt] = (f32x4){0.f,0.f,0.f,0.f};
  const u16* Ag = A + (size_t)(m0 + (t>>2))*K + (t&3)*8;
  const u16* Bg = B + (size_t)(n0 + (t>>2))*K + (t&3)*8;
  int t8 = t*8;
  int niter = K >> 5;   // always even (>=64)

  uint4 ra0, ra1, rb0, rb1;
  uint4 sa0, sa1, sb0, sb1;
  auto gload = [&](int it, uint4& a0, uint4& a1, uint4& b0, uint4& b1){
    int kb = it*32;
    a0 = *(const uint4*)(Ag + kb);
    a1 = *(const uint4*)(Ag + (size_t)64*K + kb);
    b0 = *(const uint4*)(Bg + kb);
    b1 = *(const uint4*)(Bg + (size_t)64*K + kb);
  };
  gload(0, ra0, ra1, rb0, rb1);
  gload(1, sa0, sa1, sb0, sb1);

  auto step = [&](int buf, uint4& a0, uint4& a1, uint4& b0, uint4& b1, int pf){
    *(uint4*)&SA[buf][t8]        = a0;
    *(uint4*)&SA[buf][2048 + t8] = a1;
    *(uint4*)&SB[buf][t8]        = b0;
    *(uint4*)&SB[buf][2048 + t8] = b1;
    __builtin_amdgcn_s_waitcnt(0xC07F);   // lgkmcnt(0) only
    __builtin_amdgcn_s_barrier();
    gload(pf, a0, a1, b0, b1);
    short8 af[4], bf_[4];
    #pragma unroll
    for (int mt = 0; mt < 4; ++mt) af[mt]  = *(const short8*)&SA[buf][(mw + mt*16 + lr)*32 + lg*8];
    #pragma unroll
    for (int nt = 0; nt < 4; ++nt) bf_[nt] = *(const short8*)&SB[buf][(nw + nt*16 + lr)*32 + lg*8];
    #pragma unroll
    for (int mt = 0; mt < 4; ++mt)
      #pragma unroll
      for (int nt = 0; nt < 4; ++nt)
        acc[mt][nt] = __builtin_amdgcn_mfma_f32_16x16x32_bf16(af[mt], bf_[nt], acc[mt][nt], 0, 0, 0);
  };

  for (int k = 0; k < niter; k += 2){
    step(0, ra0, ra1, rb0, rb1, (k+2 < niter) ? k+2 : k);
    step(1, sa0, sa1, sb0, sb1, (k+3 < niter) ? k+3 : k+1);
  }

  // epilogue
  u16* cb_ = C0; int ldc = N; int coff = n0;
  if (EPI == 2){
    if (n0 < 2048)      { cb_ = C0; ldc = 2048; coff = n0; }
    else if (n0 < 2560) { cb_ = C1; ldc = 512;  coff = n0 - 2048; }
    else                { cb_ = C2; ldc = 512;  coff = n0 - 2560; }
  }
  if (EPI == 3){
    if (n0 < 512)       { cb_ = C1; ldc = 512;  coff = n0; }
    else                { cb_ = C2; ldc = 512;  coff = n0 - 512; }
  }
  #pragma unroll
  for (int mt = 0; mt < 4; ++mt)
    #pragma unroll
    for (int nt = 0; nt < 4; ++nt){
      int cl = nw + nt*16 + lr;
      #pragma unroll
      for (int rg = 0; rg < 4; ++rg){
        int row = m0 + mw + mt*16 + lg*4 + rg;
        float v = acc[mt][nt][rg];
        if (EPI == 1){
          Cf[(size_t)row*N + n0 + cl] += v;
        } else if (EPI == 4){
          size_t idx = (size_t)row*ldc + coff + cl;
          float g = b2f(C1[idx]);
          cb_[idx] = f2b((g/(1.0f+__expf(-g)))*v);
        } else {
          cb_[(size_t)row*ldc + coff + cl] = f2b(v);
        }
      }
    }
}

// ---------------- skinny GEMM for M=16 (one 16x16 MFMA frag per wave)
// C = A(16 x K) @ B(N x K)^T.  OUT=0: bf16 store. OUT=1: f32 atomicAdd into Hf
// at gathered rows. OUT=3: Cb = silu(Cb)*acc. GA=1: gather A rows via rows[].
template<int OUT, int GA, int KC>
__global__ __launch_bounds__(256) void k_skinny(const u16* __restrict__ A,
      const u16* __restrict__ B, float* __restrict__ Hf, u16* __restrict__ Cb,
      const int* __restrict__ rows, int N, int K){
  int w = threadIdx.x >> 6, lane = threadIdx.x & 63;
  int lr = lane & 15, lg = lane >> 4;
  int n0 = blockIdx.x*64 + w*16;
  int kbase = blockIdx.y * KC;
  int ar = GA ? rows[lr] : lr;
  f32x4 ac0 = (f32x4){0.f,0.f,0.f,0.f};
  f32x4 ac1 = (f32x4){0.f,0.f,0.f,0.f};
  const u16* Ap = A + (size_t)ar*K + kbase + lg*8;
  const u16* Bp = B + (size_t)(n0 + lr)*K + kbase + lg*8;
  #pragma unroll 8
  for (int k = 0; k < KC; k += 64){
    ac0 = __builtin_amdgcn_mfma_f32_16x16x32_bf16(*(const short8*)(Ap + k),
            *(const short8*)(Bp + k), ac0, 0, 0, 0);
    ac1 = __builtin_amdgcn_mfma_f32_16x16x32_bf16(*(const short8*)(Ap + k + 32),
            *(const short8*)(Bp + k + 32), ac1, 0, 0, 0);
  }
  f32x4 acc = ac0 + ac1;
  #pragma unroll
  for (int rg = 0; rg < 4; ++rg){
    int m = lg*4 + rg;
    if (OUT == 0){
      Cb[(size_t)m*N + n0 + lr] = f2b(acc[rg]);
    } else if (OUT == 1){
      atomicAdd(&Hf[(size_t)rows[m]*D_ + n0 + lr], acc[rg]);
    } else {
      size_t idx = (size_t)m*N + n0 + lr;
      float g = b2f(Cb[idx]);
      Cb[idx] = f2b((g/(1.0f+__expf(-g)))*acc[rg]);
    }
  }
}

// ---------------- last-token row indices
__global__ void k_rows(const int* __restrict__ mask, int* __restrict__ rows){
  int b = threadIdx.x;
  if (b < 16){
    int c = 0;
    for (int i = 0; i < 128; ++i) c += (mask[b*128+i] > 0);
    rows[b] = b*128 + c - 1;
  }
}

// ---------------- RMSNorm on 16 gathered rows -> compact
__global__ void k_rms16(const float* __restrict__ h, const float* __restrict__ w,
                        const int* __restrict__ rows, u16* __restrict__ xq){
  __shared__ float red[4];
  int m = blockIdx.x, t = threadIdx.x;
  const float* hr = h + (size_t)rows[m] * D_;
  float ss = 0.f;
  for (int i = t; i < D_; i += 256){ float v = hr[i]; ss += v*v; }
  #pragma unroll
  for (int mm = 32; mm; mm >>= 1) ss += __shfl_xor(ss, mm, 64);
  if ((t & 63) == 0) red[t >> 6] = ss;
  __syncthreads();
  float sc = rsqrtf((red[0]+red[1]+red[2]+red[3]) * (1.0f/D_) + EPS_);
  for (int i = t; i < D_; i += 256) xq[(size_t)m*D_ + i] = f2b(hr[i]*sc*w[i]);
}

// ---------------- RoPE in-place on bf16 [tok][nh*128]
__global__ void k_rope(u16* __restrict__ x, int nh){
  int i = blockIdx.x*256 + threadIdx.x;
  int d = i & 63; int rem = i >> 6; int hh = rem % nh; int tok = rem / nh;
  int s = tok & 127;
  size_t base = (size_t)tok*nh*128 + hh*128 + d;
  float x1 = b2f(x[base]), x2 = b2f(x[base+64]);
  float inv = exp2f(-(float)d * 0.20762050581352868f);
  float ang = (float)s * inv;
  float sn = sinf(ang), cs = cosf(ang);
  x[base]      = f2b(x1*cs - x2*sn);
  x[base+64]   = f2b(x2*cs + x1*sn);
}

// ---------------- RoPE on compact q (16 rows x 16 heads x 128)
__global__ void k_rope16(u16* __restrict__ x, const int* __restrict__ rows){
  int i = blockIdx.x*256 + threadIdx.x;      // 16384 total
  int d = i & 63; int hh = (i >> 6) & 15; int m = i >> 10;
  int s = rows[m] & 127;
  size_t base = (size_t)m*2048 + hh*128 + d;
  float x1 = b2f(x[base]), x2 = b2f(x[base+64]);
  float inv = exp2f(-(float)d * 0.20762050581352868f);
  float ang = (float)s * inv;
  float sn = sinf(ang), cs = cosf(ang);
  x[base]      = f2b(x1*cs - x2*sn);
  x[base+64]   = f2b(x2*cs + x1*sn);
}

// ---------------- attention: one block per (b, head); S=128, HD=128 (full M)
__global__ __launch_bounds__(256) void k_attn(const u16* __restrict__ q,
      const u16* __restrict__ kk, const u16* __restrict__ vv,
      const int* __restrict__ mask, u16* __restrict__ ctx){
  __shared__ u16 QP[128*128];
  __shared__ u16 KV[128*128];
  int b = blockIdx.y, h = blockIdx.x;
  int t = threadIdx.x, w = t >> 6, lane = t & 63;
  int lr = lane & 15, lg = lane >> 4;
  #pragma unroll
  for (int it = 0; it < 8; ++it){
    int fi = it*256 + t; int s = fi >> 4, c8 = fi & 15;
    *(uint4*)&QP[s*128 + c8*8] = *(const uint4*)(q  + (size_t)(b*128+s)*2048 + h*128 + c8*8);
    *(uint4*)&KV[s*128 + c8*8] = *(const uint4*)(kk + (size_t)(b*128+s)*512 + (h>>2)*128 + c8*8);
  }
  __syncthreads();
  f32x4 sac[2][8];
  #pragma unroll
  for (int mt = 0; mt < 2; ++mt)
    #pragma unroll
    for (int nt = 0; nt < 8; ++nt) sac[mt][nt] = (f32x4){0.f,0.f,0.f,0.f};
  for (int ks = 0; ks < 128; ks += 32){
    short8 a[2], bb[8];
    #pragma unroll
    for (int mt = 0; mt < 2; ++mt) a[mt] = *(const short8*)&QP[(w*32 + mt*16 + lr)*128 + ks + lg*8];
    #pragma unroll
    for (int nt = 0; nt < 8; ++nt) bb[nt] = *(const short8*)&KV[(nt*16 + lr)*128 + ks + lg*8];
    #pragma unroll
    for (int mt = 0; mt < 2; ++mt)
      #pragma unroll
      for (int nt = 0; nt < 8; ++nt)
        sac[mt][nt] = __builtin_amdgcn_mfma_f32_16x16x32_bf16(a[mt], bb[nt], sac[mt][nt], 0, 0, 0);
  }
  const float NEG = -1e9f, scl = 0.08838834764831845f;
  float mbias[8];
  #pragma unroll
  for (int nt = 0; nt < 8; ++nt) mbias[nt] = (mask[b*128 + nt*16 + lr] > 0) ? 0.f : NEG;
  #pragma unroll
  for (int mt = 0; mt < 2; ++mt)
    #pragma unroll
    for (int rg = 0; rg < 4; ++rg){
      int row = w*32 + mt*16 + lg*4 + rg;
      float vvv[8]; float mx = -3e38f;
      #pragma unroll
      for (int nt = 0; nt < 8; ++nt){
        int col = nt*16 + lr;
        float s_ = sac[mt][nt][rg]*scl + ((col <= row) ? mbias[nt] : NEG);
        vvv[nt] = s_; mx = fmaxf(mx, s_);
      }
      #pragma unroll
      for (int m_ = 1; m_ < 16; m_ <<= 1) mx = fmaxf(mx, __shfl_xor(mx, m_, 64));
      float sum = 0.f;
      #pragma unroll
      for (int nt = 0; nt < 8; ++nt){ vvv[nt] = __expf(vvv[nt]-mx); sum += vvv[nt]; }
      #pragma unroll
      for (int m_ = 1; m_ < 16; m_ <<= 1) sum += __shfl_xor(sum, m_, 64);
      float inv = 1.0f/sum;
      #pragma unroll
      for (int nt = 0; nt < 8; ++nt) QP[row*128 + nt*16 + lr] = f2b(vvv[nt]*inv);
    }
  __syncthreads();
  #pragma unroll
  for (int it = 0; it < 8; ++it){
    int fi = it*256 + t; int s = fi >> 4, c8 = fi & 15;
    u16 tmp[8];
    *(uint4*)tmp = *(const uint4*)(vv + (size_t)(b*128+s)*512 + (h>>2)*128 + c8*8);
    #pragma unroll
    for (int j = 0; j < 8; ++j) KV[(c8*8+j)*128 + s] = tmp[j];
  }
  __syncthreads();
  f32x4 oac[2][8];
  #pragma unroll
  for (int mt = 0; mt < 2; ++mt)
    #pragma unroll
    for (int nt = 0; nt < 8; ++nt) oac[mt][nt] = (f32x4){0.f,0.f,0.f,0.f};
  for (int ks = 0; ks < 128; ks += 32){
    short8 a[2], bb[8];
    #pragma unroll
    for (int mt = 0; mt < 2; ++mt) a[mt] = *(const short8*)&QP[(w*32 + mt*16 + lr)*128 + ks + lg*8];
    #pragma unroll
    for (int nt = 0; nt < 8; ++nt) bb[nt] = *(const short8*)&KV[(nt*16 + lr)*128 + ks + lg*8];
    #pragma unroll
    for (int mt = 0; mt < 2; ++mt)
      #pragma unroll
      for (int nt = 0; nt < 8; ++nt)
        oac[mt][nt] = __builtin_amdgcn_mfma_f32_16x16x32_bf16(a[mt], bb[nt], oac[mt][nt], 0, 0, 0);
  }
  #pragma unroll
  for (int mt = 0; mt < 2; ++mt)
    #pragma unroll
    for (int nt = 0; nt < 8; ++nt)
      #pragma unroll
      for (int rg = 0; rg < 4; ++rg){
        int row = w*32 + mt*16 + lg*4 + rg;
        int col = nt*16 + lr;
        ctx[(size_t)(b*128+row)*2048 + h*128 + col] = f2b(oac[mt][nt][rg]);
      }
}

// ---------------- single-query attention for the 16 gathered rows
__global__ void k_attn1(const u16* __restrict__ qc, const u16* __restrict__ kk,
      const u16* __restrict__ vv, const int* __restrict__ mask,
      const int* __restrict__ rows, u16* __restrict__ out){
  __shared__ float ps[128];
  __shared__ float red2[2];
  int h = blockIdx.x, b = blockIdx.y, t = threadIdx.x;
  int pos = rows[b] & 127;
  const u16* qrow = qc + (size_t)b*2048 + h*128;
  const u16* krow = kk + (size_t)(b*128 + t)*512 + (h>>2)*128;
  float acc = 0.f;
  #pragma unroll
  for (int d0 = 0; d0 < 128; d0 += 8){
    short8 qa = *(const short8*)(qrow + d0);
    short8 ka = *(const short8*)(krow + d0);
    #pragma unroll
    for (int j = 0; j < 8; ++j) acc += b2f((u16)qa[j]) * b2f((u16)ka[j]);
  }
  bool keep = (t <= pos) && (mask[b*128 + t] > 0);
  float s_ = keep ? acc * 0.08838834764831845f : -1e9f;
  float mx = s_;
  #pragma unroll
  for (int m_ = 1; m_ < 64; m_ <<= 1) mx = fmaxf(mx, __shfl_xor(mx, m_, 64));
  if ((t & 63) == 0) red2[t >> 6] = mx;
  __syncthreads();
  mx = fmaxf(red2[0], red2[1]);
  float p = __expf(s_ - mx);
  float sum = p;
  #pragma unroll
  for (int m_ = 1; m_ < 64; m_ <<= 1) sum += __shfl_xor(sum, m_, 64);
  __syncthreads();
  if ((t & 63) == 0) red2[t >> 6] = sum;
  __syncthreads();
  float inv = 1.f / (red2[0] + red2[1]);
  ps[t] = p * inv;
  __syncthreads();
  float o = 0.f;
  const u16* vbase = vv + (size_t)b*128*512 + (h>>2)*128 + t;
  for (int s = 0; s < 128; s += 4){
    o += ps[s]   * b2f(vbase[(size_t)(s  )*512]);
    o += ps[s+1] * b2f(vbase[(size_t)(s+1)*512]);
    o += ps[s+2] * b2f(vbase[(size_t)(s+2)*512]);
    o += ps[s+3] * b2f(vbase[(size_t)(s+3)*512]);
  }
  out[(size_t)b*2048 + h*128 + t] = f2b(o);
}

// ---------------- final norm + last-token gather
__global__ void k_final(const float* __restrict__ h, const int* __restrict__ mask,
                        const float* __restrict__ w, float* __restrict__ out){
  __shared__ float red[4]; __shared__ int rowsh;
  int b = blockIdx.x, t = threadIdx.x;
  if (t == 0){
    int c = 0;
    for (int i = 0; i < 128; ++i) c += (mask[b*128+i] > 0);
    rowsh = b*128 + c - 1;
  }
  __syncthreads();
  const float* hr = h + (size_t)rowsh*D_;
  float ss = 0.f;
  for (int i = t; i < D_; i += 256){ float x = hr[i]; ss += x*x; }
  #pragma unroll
  for (int m = 32; m; m >>= 1) ss += __shfl_xor(ss, m, 64);
  if ((t & 63) == 0) red[t >> 6] = ss;
  __syncthreads();
  float sc = rsqrtf((red[0]+red[1]+red[2]+red[3]) * (1.0f/D_) + EPS_);
  for (int i = t; i < D_; i += 256) out[(size_t)b*D_ + i] = hr[i]*sc*w[i];
}

extern "C" void kernel_launch(void* const* d_in, const int* in_sizes, int n_in,
                              void* d_out, int out_size, void* d_ws, size_t ws_size,
                              hipStream_t stream) {
  const int*   ids       = (const int*)  d_in[0];
  const int*   mask      = (const int*)  d_in[1];
  const float* embed     = (const float*)d_in[2];
  const float* attn_norm = (const float*)d_in[3];
  const float* mlp_norm  = (const float*)d_in[4];
  const float* fin_norm  = (const float*)d_in[5];
  struct QW { const int* c; const float* am; const float* A; const float* B; };
  auto qw = [&](int i){ return QW{(const int*)d_in[i], (const float*)d_in[i+1],
                                  (const float*)d_in[i+2], (const float*)d_in[i+3]}; };
  QW Wq = qw(6), Wk = qw(10), Wv = qw(14), Wo = qw(18), Wg = qw(22), Wu = qw(26), Wd = qw(30);

  // workspace layout
  char* ws = (char*)d_ws;
  float* h  = (float*)(ws);                       // 16 MB
  u16* xb   = (u16*)(ws + 16777216);              // 8 MB (x / ctx)
  u16* qb   = (u16*)(ws + 25165824);              // 8 MB
  u16* kb_  = (u16*)(ws + 33554432);              // 2 MB
  u16* vb   = (u16*)(ws + 35651584);              // 2 MB
  u16* gb   = (u16*)(ws + 37748736);              // 32 MB
  u16* Wb   = (u16*)(ws + 104857600);             // 32 MB (folded weights)
  // compact (layer-1) buffers
  int* rowsi = (int*)(ws + 138412032);            // 64 B
  u16* xq    = (u16*)(ws + 138413056);            // 64 KB
  u16* qc    = (u16*)(ws + 138478592);            // 64 KB
  u16* cc    = (u16*)(ws + 138544128);            // 64 KB
  u16* g16   = (u16*)(ws + 138609664);            // 256 KB
  u16* Wb2   = (u16*)(ws + 167772160);            // 32 MB (second folded buffer)

  auto fs = [&](QW W_, int l, int O, int I, u16* dst){
    return FoldSet{ W_.c + (size_t)l*O*I, W_.am + (size_t)l*O*(I>>6),
                    W_.A + (size_t)l*R_*I, W_.B + (size_t)l*O*R_, dst };
  };

  k_embed<<<NTOK_, 256, 0, stream>>>(ids, embed, h);

  for (int l = 0; l < 2; ++l){
    // ---- attention block: fold q,k,v stacked into Wb (3072 x 2048), one launch
    k_rms<<<NTOK_, 256, 0, stream>>>(h, attn_norm + l*D_, xb);
    {
      FoldSet fq = fs(Wq, l, D_, D_, Wb);
      FoldSet fk = fs(Wk, l, 512, D_, Wb + (size_t)2048*D_);
      FoldSet fv = fs(Wv, l, 512, D_, Wb + (size_t)2560*D_);
      k_fold3<<<dim3(16,24), 256, 0, stream>>>(fq, fk, fv, 16, 20, D_);
    }

    if (l == 0){
      k_gemm<2><<<dim3(24,16), 256, 0, stream>>>(xb, Wb, nullptr, qb, kb_, vb, NTOK_, 3072, D_);
      k_rope<<<8192, 256, 0, stream>>>(qb, H_);
      k_rope<<<2048, 256, 0, stream>>>(kb_, HK_);
      k_attn<<<dim3(16,16), 256, 0, stream>>>(qb, kb_, vb, mask, xb);  // ctx -> xb
      {
        FoldSet fo = fs(Wo, l, D_, D_, Wb);
        k_fold3<<<dim3(16,16), 256, 0, stream>>>(fo, fo, fo, 9999, 9999, D_);
      }
      k_gemm<1><<<dim3(16,16), 256, 0, stream>>>(xb, Wb, h, nullptr, nullptr, nullptr, NTOK_, D_, D_);
      // ---- MLP block: gate->Wb, up->Wb2, one fold launch
      k_rms<<<NTOK_, 256, 0, stream>>>(h, mlp_norm + l*D_, xb);
      {
        FoldSet fg = fs(Wg, l, F_, D_, Wb);
        FoldSet fu = fs(Wu, l, F_, D_, Wb2);
        k_fold3<<<dim3(16,128), 256, 0, stream>>>(fg, fu, fu, 64, 64, D_);
      }
      k_gemm<0><<<dim3(64,16), 256, 0, stream>>>(xb, Wb,  nullptr, gb, nullptr, nullptr, NTOK_, F_, D_);
      k_gemm<4><<<dim3(64,16), 256, 0, stream>>>(xb, Wb2, nullptr, gb, gb, nullptr, NTOK_, F_, D_);
      {
        FoldSet fd = fs(Wd, l, D_, F_, Wb);
        k_fold3<<<dim3(64,16), 256, 0, stream>>>(fd, fd, fd, 9999, 9999, F_);
      }
      k_gemm<1><<<dim3(16,16), 256, 0, stream>>>(gb, Wb, h, nullptr, nullptr, nullptr, NTOK_, D_, F_);
    } else {
      // last layer: only the 16 last-token rows feed the output.
      k_gemm<3><<<dim3(8,16), 256, 0, stream>>>(xb, Wb + (size_t)2048*D_, nullptr, nullptr,
          kb_, vb, NTOK_, 1024, D_);
      k_rows<<<1, 64, 0, stream>>>(mask, rowsi);
      k_skinny<0,1,2048><<<dim3(32,1), 256, 0, stream>>>(xb, Wb, nullptr, qc, rowsi, D_, D_);
      k_rope16<<<64, 256, 0, stream>>>(qc, rowsi);
      k_rope<<<2048, 256, 0, stream>>>(kb_, HK_);
      k_attn1<<<dim3(16,16), 128, 0, stream>>>(qc, kb_, vb, mask, rowsi, cc);
      {
        FoldSet fo = fs(Wo, l, D_, D_, Wb);
        k_fold3<<<dim3(16,16), 256, 0, stream>>>(fo, fo, fo, 9999, 9999, D_);
      }
      k_skinny<1,0,2048><<<dim3(32,1), 256, 0, stream>>>(cc, Wb, h, nullptr, rowsi, D_, D_);
      // ---- MLP on 16 rows
      k_rms16<<<16, 256, 0, stream>>>(h, mlp_norm + l*D_, rowsi, xq);
      {
        FoldSet fg = fs(Wg, l, F_, D_, Wb);
        FoldSet fu = fs(Wu, l, F_, D_, Wb2);
        k_fold3<<<dim3(16,128), 256, 0, stream>>>(fg, fu, fu, 64, 64, D_);
      }
      k_skinny<0,0,2048><<<dim3(128,1), 256, 0, stream>>>(xq, Wb,  nullptr, g16, rowsi, F_, D_);
      k_skinny<3,0,2048><<<dim3(128,1), 256, 0, stream>>>(xq, Wb2, nullptr, g16, rowsi, F_, D_);
      {
        FoldSet fd = fs(Wd, l, D_, F_, Wb);
        k_fold3<<<dim3(64,16), 256, 0, stream>>>(fd, fd, fd, 9999, 9999, F_);
      }
      k_skinny<1,0,2048><<<dim3(32,4), 256, 0, stream>>>(g16, Wb, h, nullptr, rowsi, D_, F_);
    }
  }
  k_final<<<16, 256, 0, stream>>>(h, mask, fin_norm, (float*)d_out);
}